// Round 11
// baseline (35.165 us; speedup 1.0000x reference)
//
#include <hip/hip_runtime.h>

// B=256, L=2048, K=8. Output (B,2) float32.
constexpr int BB = 256;
constexpr int LL = 2048;
constexpr int KK = 8;
constexpr int THREADS = 1024;
constexpr int SPLIT = 2;               // blocks per batch -> 512 blocks = 2/CU
constexpr double INV_SQRT2 = 0.7071067811865476;

typedef float f4 __attribute__((ext_vector_type(4)));

// Ring = Z[t]/(t^4+1) in basis (1, t, t^2, -t^3): commutative+associative.
// |z components| <= 4 after pow2-strip; butterfly levels bound 64, 16384;
// __mul24 exact for |operands| <= 2^14, sums <= 2^30 < 2^31.
// Identity: 2^minp * sum_l pc*2^(pp-minp) == sum_l pc*2^pp -> per-batch
// reduction over L, no cross-l coupling.

__device__ __forceinline__ void ring_mul(int& ra, int& rb, int& rc, int& rd,
                                         int A, int Bv, int C, int D) {
    const int nA = __mul24(ra, A)  + __mul24(rb, D)  - __mul24(rc, C)  + __mul24(rd, Bv);
    const int nB = __mul24(ra, Bv) + __mul24(rb, A)  + __mul24(rc, D)  + __mul24(rd, C);
    const int nC = __mul24(ra, C)  + __mul24(rb, Bv) + __mul24(rc, A)  - __mul24(rd, D);
    const int nD = __mul24(ra, D)  - __mul24(rb, C)  - __mul24(rc, Bv) + __mul24(rd, A);
    ra = nA; rb = nB; rc = nC; rd = nD;
}

// lane = l_sub*8 + k within the wave; one call handles 8 l's x 8 k's.
__device__ __forceinline__ void process(const f4 u, const f4 v, int p,
                                        const int lane, double& accR, double& accI) {
    const int a1 = (int)u.x, b1 = (int)u.y, g1 = (int)u.z, e1 = (int)u.w;
    const int a2 = (int)v.x, b2 = (int)v.y, g2 = (int)v.z, e2 = (int)v.w;

    int A  = __mul24(a1,a2) + __mul24(b1,e2) - __mul24(g1,g2) + __mul24(e1,b2);
    int Bv = __mul24(a1,b2) + __mul24(b1,a2) + __mul24(g1,e2) + __mul24(e1,g2);
    int C  = __mul24(a1,g2) + __mul24(b1,b2) + __mul24(g1,a2) - __mul24(e1,e2);
    int D  = __mul24(a1,e2) - __mul24(b1,g2) - __mul24(g1,b2) + __mul24(e1,a2);

    // strip common powers of two
    const int m = A | Bv | C | D;
    const int s = (m == 0) ? 0 : __builtin_ctz(m);
    A >>= s; Bv >>= s; C >>= s; D >>= s;
    p += s;

    // butterfly product over the 8-lane k-group (xor 1,2,4)
    #pragma unroll
    for (int off = 1; off < 8; off <<= 1) {
        const int oa = __shfl_xor(A,  off, 64);
        const int ob = __shfl_xor(Bv, off, 64);
        const int oc = __shfl_xor(C,  off, 64);
        const int od = __shfl_xor(D,  off, 64);
        const int op = __shfl_xor(p,  off, 64);
        ring_mul(A, Bv, C, D, oa, ob, oc, od);
        p += op;
    }

    // 2^p (p in [0,32]) via exponent bits; only the k==0 lane of each group adds
    const unsigned long long bits = ((unsigned long long)(1023 + p)) << 52;
    const double w = ((lane & 7) == 0) ? __longlong_as_double((long long)bits) : 0.0;
    const double dA = (double)A, dB = (double)Bv, dC = (double)C, dD = (double)D;
    accR += w * (dA + (dB + dD) * INV_SQRT2);
    accI += w * (dC + (dB - dD) * INV_SQRT2);
}

// one tile: 2 k-groups (16 l's per wave), 8 nontemporal load instructions
struct Tile {
    f4 u0, v0, u1, v1;
    int pa0, pb0, pa1, pb1;
};

__device__ __forceinline__ Tile load_tile(const f4* __restrict__ c1,
                                          const f4* __restrict__ c2,
                                          const int* __restrict__ p1,
                                          const int* __restrict__ p2,
                                          long long i0) {
    Tile t;
    t.u0 = __builtin_nontemporal_load(&c1[i0]);
    t.v0 = __builtin_nontemporal_load(&c2[i0]);
    t.u1 = __builtin_nontemporal_load(&c1[i0 + 64]);
    t.v1 = __builtin_nontemporal_load(&c2[i0 + 64]);
    t.pa0 = __builtin_nontemporal_load(&p1[i0]);
    t.pb0 = __builtin_nontemporal_load(&p2[i0]);
    t.pa1 = __builtin_nontemporal_load(&p1[i0 + 64]);
    t.pb1 = __builtin_nontemporal_load(&p2[i0 + 64]);
    return t;
}

__global__ __launch_bounds__(THREADS) void esa_kernel(
    const f4* __restrict__ c1,
    const f4* __restrict__ c2,
    const int*  __restrict__ p1,
    const int*  __restrict__ p2,
    double* __restrict__ ws_part) {    // (BB*SPLIT) double2 partials
    const int b    = blockIdx.x >> 1;          // SPLIT = 2
    const int half = blockIdx.x & 1;
    const int tid  = threadIdx.x;
    const int wave = tid >> 6;                 // 0..15
    const int lane = tid & 63;

    constexpr int NW    = THREADS / 64;              // 16 waves
    constexpr int LSPAN = LL / SPLIT;                // 1024 l's per block
    constexpr int GRP   = 2;                         // k-groups per tile
    constexpr int LPW   = 8 * GRP;                   // 16 l's per wave per tile
    constexpr int LPB   = NW * LPW;                  // 256 l's per block per tile
    constexpr int ITERS = LSPAN / LPB;               // 4

    double accR = 0.0, accI = 0.0;

    const long long i0 = ((long long)b * LL + half * LSPAN + wave * LPW) * KK + lane;

    Tile cur = load_tile(c1, c2, p1, p2, i0);
    #pragma unroll
    for (int it = 0; it < ITERS; ++it) {
        Tile nxt;
        if (it + 1 < ITERS)
            nxt = load_tile(c1, c2, p1, p2, i0 + (long long)(it + 1) * LPB * KK);
        process(cur.u0, cur.v0, cur.pa0 + cur.pb0, lane, accR, accI);
        process(cur.u1, cur.v1, cur.pa1 + cur.pb1, lane, accR, accI);
        if (it + 1 < ITERS) cur = nxt;
    }

    // wave reduce then LDS across waves
    for (int off = 32; off > 0; off >>= 1) {
        accR += __shfl_down(accR, off, 64);
        accI += __shfl_down(accI, off, 64);
    }
    __shared__ double sR[NW], sI[NW];
    if (lane == 0) { sR[wave] = accR; sI[wave] = accI; }
    __syncthreads();
    if (tid == 0) {
        double tR = 0.0, tI = 0.0;
        #pragma unroll
        for (int w = 0; w < NW; ++w) { tR += sR[w]; tI += sI[w]; }
        // plain store: every byte of the partial array written every call
        ws_part[(size_t)blockIdx.x * 2 + 0] = tR;
        ws_part[(size_t)blockIdx.x * 2 + 1] = tI;
    }
}

// sum SPLIT partials per batch in fixed order; 1 block x 256 threads
__global__ __launch_bounds__(BB) void esa_reduce(
    const double* __restrict__ ws_part,
    float* __restrict__ out) {
    const int b = threadIdx.x;     // 0..255
    double tR = 0.0, tI = 0.0;
    #pragma unroll
    for (int part = 0; part < SPLIT; ++part) {
        tR += ws_part[((size_t)(b * SPLIT + part)) * 2 + 0];
        tI += ws_part[((size_t)(b * SPLIT + part)) * 2 + 1];
    }
    out[b * 2 + 0] = (float)tR;
    out[b * 2 + 1] = (float)tI;
}

extern "C" void kernel_launch(void* const* d_in, const int* in_sizes, int n_in,
                              void* d_out, int out_size, void* d_ws, size_t ws_size,
                              hipStream_t stream) {
    const f4*     c1 = (const f4*)d_in[0];
    const f4*     c2 = (const f4*)d_in[1];
    const int*    p1 = (const int*)d_in[2];
    const int*    p2 = (const int*)d_in[3];
    float*  out = (float*)d_out;
    double* ws  = (double*)d_ws;   // BB*SPLIT*2 doubles = 8 KB

    esa_kernel<<<BB * SPLIT, THREADS, 0, stream>>>(c1, c2, p1, p2, ws);
    esa_reduce<<<1, BB, 0, stream>>>(ws, out);
}

// Round 12
// 30.093 us; speedup vs baseline: 1.1685x; 1.1685x over previous
//
#include <hip/hip_runtime.h>

// B=256, L=2048, K=8. Output (B,2) float32.
constexpr int BB = 256;
constexpr int LL = 2048;
constexpr int KK = 8;
constexpr int THREADS = 1024;
constexpr double INV_SQRT2 = 0.7071067811865476;

typedef float f4 __attribute__((ext_vector_type(4)));

// Ring = Z[t]/(t^4+1) in basis (1, t, t^2, -t^3): commutative+associative.
// |z components| <= 4 after pow2-strip; butterfly levels bound 64, 16384;
// __mul24 exact for |operands| <= 2^14, sums <= 2^30 < 2^31.
// Identity: 2^minp * sum_l pc*2^(pp-minp) == sum_l pc*2^pp -> per-batch
// reduction over L, no cross-l coupling.

__device__ __forceinline__ void ring_mul(int& ra, int& rb, int& rc, int& rd,
                                         int A, int Bv, int C, int D) {
    const int nA = __mul24(ra, A)  + __mul24(rb, D)  - __mul24(rc, C)  + __mul24(rd, Bv);
    const int nB = __mul24(ra, Bv) + __mul24(rb, A)  + __mul24(rc, D)  + __mul24(rd, C);
    const int nC = __mul24(ra, C)  + __mul24(rb, Bv) + __mul24(rc, A)  - __mul24(rd, D);
    const int nD = __mul24(ra, D)  - __mul24(rb, C)  - __mul24(rc, Bv) + __mul24(rd, A);
    ra = nA; rb = nB; rc = nC; rd = nD;
}

// lane = l_sub*8 + k within the wave; one call handles 8 l's x 8 k's.
__device__ __forceinline__ void process(const f4 u, const f4 v, int p,
                                        const int lane, double& accR, double& accI) {
    const int a1 = (int)u.x, b1 = (int)u.y, g1 = (int)u.z, e1 = (int)u.w;
    const int a2 = (int)v.x, b2 = (int)v.y, g2 = (int)v.z, e2 = (int)v.w;

    int A  = __mul24(a1,a2) + __mul24(b1,e2) - __mul24(g1,g2) + __mul24(e1,b2);
    int Bv = __mul24(a1,b2) + __mul24(b1,a2) + __mul24(g1,e2) + __mul24(e1,g2);
    int C  = __mul24(a1,g2) + __mul24(b1,b2) + __mul24(g1,a2) - __mul24(e1,e2);
    int D  = __mul24(a1,e2) - __mul24(b1,g2) - __mul24(g1,b2) + __mul24(e1,a2);

    // strip common powers of two
    const int m = A | Bv | C | D;
    const int s = (m == 0) ? 0 : __builtin_ctz(m);
    A >>= s; Bv >>= s; C >>= s; D >>= s;
    p += s;

    // butterfly product over the 8-lane k-group (xor 1,2,4)
    #pragma unroll
    for (int off = 1; off < 8; off <<= 1) {
        const int oa = __shfl_xor(A,  off, 64);
        const int ob = __shfl_xor(Bv, off, 64);
        const int oc = __shfl_xor(C,  off, 64);
        const int od = __shfl_xor(D,  off, 64);
        const int op = __shfl_xor(p,  off, 64);
        ring_mul(A, Bv, C, D, oa, ob, oc, od);
        p += op;
    }

    // 2^p (p in [0,32]) via exponent bits; only the k==0 lane of each group adds
    const unsigned long long bits = ((unsigned long long)(1023 + p)) << 52;
    const double w = ((lane & 7) == 0) ? __longlong_as_double((long long)bits) : 0.0;
    const double dA = (double)A, dB = (double)Bv, dC = (double)C, dD = (double)D;
    accR += w * (dA + (dB + dD) * INV_SQRT2);
    accI += w * (dC + (dB - dD) * INV_SQRT2);
}

// one tile: 2 k-groups (16 l's per wave), 8 nontemporal load instructions
struct Tile {
    f4 u0, v0, u1, v1;
    int pa0, pb0, pa1, pb1;
};

__device__ __forceinline__ Tile load_tile(const f4* __restrict__ c1,
                                          const f4* __restrict__ c2,
                                          const int* __restrict__ p1,
                                          const int* __restrict__ p2,
                                          long long i0) {
    Tile t;
    t.u0 = __builtin_nontemporal_load(&c1[i0]);
    t.v0 = __builtin_nontemporal_load(&c2[i0]);
    t.u1 = __builtin_nontemporal_load(&c1[i0 + 64]);
    t.v1 = __builtin_nontemporal_load(&c2[i0 + 64]);
    t.pa0 = __builtin_nontemporal_load(&p1[i0]);
    t.pb0 = __builtin_nontemporal_load(&p2[i0]);
    t.pa1 = __builtin_nontemporal_load(&p1[i0 + 64]);
    t.pb1 = __builtin_nontemporal_load(&p2[i0 + 64]);
    return t;
}

__global__ __launch_bounds__(THREADS, 2) void esa_kernel(
    const f4* __restrict__ c1,
    const f4* __restrict__ c2,
    const int*  __restrict__ p1,
    const int*  __restrict__ p2,
    float* __restrict__ out) {
    const int b    = blockIdx.x;               // one block per batch
    const int tid  = threadIdx.x;
    const int wave = tid >> 6;                 // 0..15
    const int lane = tid & 63;

    constexpr int NW    = THREADS / 64;              // 16 waves
    constexpr int GRP   = 2;                         // k-groups per tile
    constexpr int LPW   = 8 * GRP;                   // 16 l's per wave per tile
    constexpr int LPB   = NW * LPW;                  // 256 l's per block per tile
    constexpr int ITERS = LL / LPB;                  // 8

    double accR = 0.0, accI = 0.0;

    const long long i0 = ((long long)b * LL + wave * LPW) * KK + lane;

    // software pipeline: prefetch tile it+1 while processing tile it
    Tile cur = load_tile(c1, c2, p1, p2, i0);
    #pragma unroll
    for (int it = 0; it < ITERS; ++it) {
        Tile nxt;
        if (it + 1 < ITERS)
            nxt = load_tile(c1, c2, p1, p2, i0 + (long long)(it + 1) * LPB * KK);
        process(cur.u0, cur.v0, cur.pa0 + cur.pb0, lane, accR, accI);
        process(cur.u1, cur.v1, cur.pa1 + cur.pb1, lane, accR, accI);
        if (it + 1 < ITERS) cur = nxt;
    }

    // wave reduce then LDS across waves
    for (int off = 32; off > 0; off >>= 1) {
        accR += __shfl_down(accR, off, 64);
        accI += __shfl_down(accI, off, 64);
    }
    __shared__ double sR[NW], sI[NW];
    if (lane == 0) { sR[wave] = accR; sI[wave] = accI; }
    __syncthreads();
    if (tid == 0) {
        double tR = 0.0, tI = 0.0;
        #pragma unroll
        for (int w = 0; w < NW; ++w) { tR += sR[w]; tI += sI[w]; }
        out[b * 2 + 0] = (float)tR;
        out[b * 2 + 1] = (float)tI;
    }
}

extern "C" void kernel_launch(void* const* d_in, const int* in_sizes, int n_in,
                              void* d_out, int out_size, void* d_ws, size_t ws_size,
                              hipStream_t stream) {
    const f4*     c1 = (const f4*)d_in[0];
    const f4*     c2 = (const f4*)d_in[1];
    const int*    p1 = (const int*)d_in[2];
    const int*    p2 = (const int*)d_in[3];
    float* out = (float*)d_out;

    esa_kernel<<<BB, THREADS, 0, stream>>>(c1, c2, p1, p2, out);
}